// Round 4
// baseline (619.991 us; speedup 1.0000x reference)
//
#include <hip/hip_runtime.h>

// GAAPAttention: q=xWq+bq, k=xWk+bk, v=xWv+bv; attn=softmax(qk^T);
// out = ((attn v)Wa + ba) * alpha * x.   B=8, T=4096, C=128, fp32 in/out.
// bf16 MFMA everywhere. Flash v3: swapped QK^T (P lane-local), no-max
// softmax (scores bounded ~22 -> exp fits fp32; denominator deferred to
// epilogue), T14 staging (loads issued before compute, ds_write next iter),
// XCD-pinned 1-D grid. No global_load_lds / raw asm this round (isolating
// the round-3 fault).

typedef short short8 __attribute__((ext_vector_type(8)));
typedef float f32x4 __attribute__((ext_vector_type(4)));

constexpr int BB = 8;
constexpr int TT = 4096;
constexpr int CC = 128;

__device__ inline unsigned int f2bf(float f) {
  union { float f; unsigned int u; } c; c.f = f;
  unsigned int u = c.u;
  u += 0x7fffu + ((u >> 16) & 1u);   // RTNE
  return u >> 16;
}

// ---------------------------------------------------------------------------
// K0: weight prep — transpose Wq,Wk,Wv,Wa (128x128 f32) to bf16 [f][c].
// ---------------------------------------------------------------------------
__global__ __launch_bounds__(256) void wprep_kernel(
    const float* __restrict__ Wq, const float* __restrict__ Wk,
    const float* __restrict__ Wv, const float* __restrict__ Wa,
    unsigned short* __restrict__ Wt)
{
  __shared__ unsigned short ld[128 * 136];
  const int t = threadIdx.x;
  const int m = blockIdx.x;
  const float* W = (m == 0) ? Wq : (m == 1) ? Wk : (m == 2) ? Wv : Wa;
  unsigned short* o = Wt + (size_t)m * CC * CC;
#pragma unroll
  for (int i = 0; i < 16; ++i) {
    int chunk = t + 256 * i;
    int c = chunk >> 5, f4 = (chunk & 31) * 4;
    float4 v = *(const float4*)(W + (size_t)c * CC + f4);
    uint2 u;
    u.x = f2bf(v.x) | (f2bf(v.y) << 16);
    u.y = f2bf(v.z) | (f2bf(v.w) << 16);
    *(uint2*)(ld + c * 136 + f4) = u;
  }
  __syncthreads();
#pragma unroll
  for (int i = 0; i < 16; ++i) {
    int chunk = t + 256 * i;
    int f = chunk >> 5, c4 = (chunk & 31) * 4;
    unsigned int a0 = ld[(c4 + 0) * 136 + f];
    unsigned int a1 = ld[(c4 + 1) * 136 + f];
    unsigned int a2 = ld[(c4 + 2) * 136 + f];
    unsigned int a3 = ld[(c4 + 3) * 136 + f];
    uint2 u;
    u.x = a0 | (a1 << 16);
    u.y = a2 | (a3 << 16);
    *(uint2*)(o + f * CC + c4) = u;
  }
}

// ---------------------------------------------------------------------------
// K1: fused QKV projection. grid 256, block 256 (4 waves). x staged ONCE per
// block (bf16, swizzled), then loop m=0..2 staging W^T[m] and computing.
// ---------------------------------------------------------------------------
__global__ __launch_bounds__(256) void qkv_kernel(
    const float* __restrict__ x, const unsigned short* __restrict__ Wt,
    const float* __restrict__ bq, const float* __restrict__ bk,
    const float* __restrict__ bv,
    unsigned short* __restrict__ Qo, unsigned short* __restrict__ Ko,
    unsigned short* __restrict__ Vo)
{
  __shared__ unsigned short xs[128 * 128];  // [row][c], 256B rows, ^((r&7)<<4)
  __shared__ unsigned short wt[128 * 128];  // W^T [f][c], same swizzle
  const int t = threadIdx.x;
  const int tile = blockIdx.x;

#pragma unroll
  for (int i = 0; i < 16; ++i) {
    int chunk = t + 256 * i;
    int row = chunk >> 5, c4 = chunk & 31;
    float4 v = *(const float4*)(x + (size_t)(tile * 128 + row) * CC + c4 * 4);
    uint2 u;
    u.x = f2bf(v.x) | (f2bf(v.y) << 16);
    u.y = f2bf(v.z) | (f2bf(v.w) << 16);
    unsigned int byte = (unsigned)(row * 256 + c4 * 8) ^ (((unsigned)row & 7) << 4);
    *(uint2*)((char*)xs + byte) = u;
  }

  const int w = t >> 6, l = t & 63, lr = l & 15, lh = l >> 4;

#pragma unroll
  for (int m = 0; m < 3; ++m) {
    __syncthreads();   // m=0: xs visible; m>0: prior wt reads complete
#pragma unroll
    for (int i = 0; i < 8; ++i) {
      int chunk = t + 256 * i;
      int f = chunk >> 4, c16 = chunk & 15;
      uint4 d = *(const uint4*)(Wt + (size_t)m * CC * CC + (size_t)f * CC + c16 * 8);
      unsigned int byte = (unsigned)(f * 256 + c16 * 16) ^ (((unsigned)f & 7) << 4);
      *(uint4*)((char*)wt + byte) = d;
    }
    __syncthreads();

    const float* bias = (m == 0) ? bq : (m == 1) ? bk : bv;
    unsigned short* out = (m == 0) ? Qo : (m == 1) ? Ko : Vo;

    f32x4 acc[2][8];
#pragma unroll
    for (int a = 0; a < 2; ++a)
#pragma unroll
      for (int n = 0; n < 8; ++n) acc[a][n] = (f32x4){0.f, 0.f, 0.f, 0.f};

#pragma unroll
    for (int kk = 0; kk < 4; ++kk) {
      short8 a[2];
#pragma unroll
      for (int rb = 0; rb < 2; ++rb) {
        int row = w * 32 + rb * 16 + lr;
        unsigned int byte = (unsigned)(row * 256 + kk * 64 + lh * 16) ^ (((unsigned)row & 7) << 4);
        a[rb] = *(const short8*)((const char*)xs + byte);
      }
#pragma unroll
      for (int n = 0; n < 8; ++n) {
        int row = n * 16 + lr;
        unsigned int byte = (unsigned)(row * 256 + kk * 64 + lh * 16) ^ (((unsigned)row & 7) << 4);
        short8 bfr = *(const short8*)((const char*)wt + byte);
        acc[0][n] = __builtin_amdgcn_mfma_f32_16x16x32_bf16(a[0], bfr, acc[0][n], 0, 0, 0);
        acc[1][n] = __builtin_amdgcn_mfma_f32_16x16x32_bf16(a[1], bfr, acc[1][n], 0, 0, 0);
      }
    }
#pragma unroll
    for (int n = 0; n < 8; ++n) {
      int col = n * 16 + lr;
      float bc = bias[col];
#pragma unroll
      for (int rb = 0; rb < 2; ++rb)
#pragma unroll
        for (int r = 0; r < 4; ++r) {
          int row = tile * 128 + w * 32 + rb * 16 + lh * 4 + r;
          out[(size_t)row * CC + col] = (unsigned short)f2bf(acc[rb][n][r] + bc);
        }
    }
  }
}

// ---------------------------------------------------------------------------
// K2: V transpose  V[b][t][d] -> Vt[b][d][t].
// ---------------------------------------------------------------------------
__global__ __launch_bounds__(256) void vtrans_kernel(
    const unsigned short* __restrict__ V, unsigned short* __restrict__ Vt)
{
  __shared__ unsigned short tile[64 * 136];
  const int t = threadIdx.x;
  const int b = blockIdx.y;
  const int kv0 = blockIdx.x * 64;
  const unsigned short* Vb = V + (size_t)b * TT * CC;
  unsigned short* Vtb = Vt + (size_t)b * TT * CC;
#pragma unroll
  for (int i = 0; i < 4; ++i) {
    int chunk = t + 256 * i;
    int row = chunk >> 4, c16 = chunk & 15;
    uint4 d = *(const uint4*)(Vb + (size_t)(kv0 + row) * CC + c16 * 8);
    *(uint4*)(tile + row * 136 + c16 * 8) = d;
  }
  __syncthreads();
#pragma unroll
  for (int i = 0; i < 4; ++i) {
    int chunk = t + 256 * i;
    int dd = chunk >> 3, kc = chunk & 7;
    unsigned short tmp[8];
#pragma unroll
    for (int j = 0; j < 8; ++j) tmp[j] = tile[(kc * 8 + j) * 136 + dd];
    uint4 u;
    u.x = (unsigned)tmp[0] | ((unsigned)tmp[1] << 16);
    u.y = (unsigned)tmp[2] | ((unsigned)tmp[3] << 16);
    u.z = (unsigned)tmp[4] | ((unsigned)tmp[5] << 16);
    u.w = (unsigned)tmp[6] | ((unsigned)tmp[7] << 16);
    *(uint4*)(Vtb + (size_t)dd * TT + kv0 + kc * 8) = u;
  }
}

// ---------------------------------------------------------------------------
// K3: flash attention v3.  grid 512 (b = bid&7 -> XCD pin), block 128
// (2 waves x 32 q-rows).  Swapped QK^T: s = mfma(K, Q) so lane owns q=lane&15;
// p = exp(s) lane-local, denominator summed per-lane, reduced once at end.
// Staging: reg->ds_write single buffer, 2 barriers/iter; next-tile global
// loads issued before compute (latency hides under MFMA+exp).
// ---------------------------------------------------------------------------
__global__ __launch_bounds__(128) void flash_kernel(
    const unsigned short* __restrict__ Q,
    const unsigned short* __restrict__ K,
    const unsigned short* __restrict__ Vt,
    unsigned short* __restrict__ AO)
{
  __shared__ unsigned short kt[32 * 128];   // [kv][d] 256B rows, ^((r&7)<<4)
  __shared__ unsigned short vt[128 * 32];   // [d][kv] 64B rows, ^(((r>>1)&3)<<4)
  __shared__ unsigned short ps[2][32 * 32]; // per-wave P[q][kv], 64B rows, same swz
  const int t = threadIdx.x, w = t >> 6, l = t & 63, lr = l & 15, lh = l >> 4;
  const int bid = blockIdx.x;
  const int b = bid & 7;
  const int q0 = (bid >> 3) * 64;
  const unsigned short* Qb  = Q  + (size_t)b * TT * CC;
  const unsigned short* Kb  = K  + (size_t)b * TT * CC;
  const unsigned short* Vtb = Vt + (size_t)b * TT * CC;

  // Q B-fragments: col=q-row=lr, k=lh*8+j
  short8 qf[2][4];
#pragma unroll
  for (int rb = 0; rb < 2; ++rb) {
    int qrow = q0 + w * 32 + rb * 16 + lr;
#pragma unroll
    for (int kk = 0; kk < 4; ++kk)
      qf[rb][kk] = *(const short8*)(Qb + (size_t)qrow * CC + kk * 32 + lh * 8);
  }

  // staging geometry: 4 chunks of 16B each for K (8KB) and V (8KB)
  int krow_[4], kc_[4], drow_[4], vc_[4];
  unsigned int kdst_[4], vdst_[4];
#pragma unroll
  for (int jj = 0; jj < 4; ++jj) {
    int chunk = jj * 128 + t;
    krow_[jj] = chunk >> 4; kc_[jj] = chunk & 15;
    kdst_[jj] = ((unsigned)(krow_[jj] * 256 + kc_[jj] * 16)) ^ (((unsigned)krow_[jj] & 7) << 4);
    drow_[jj] = chunk >> 2; vc_[jj] = chunk & 3;
    vdst_[jj] = ((unsigned)(drow_[jj] * 64 + vc_[jj] * 16)) ^ ((((unsigned)drow_[jj] >> 1) & 3) << 4);
  }

  f32x4 ao[2][8];
#pragma unroll
  for (int rb = 0; rb < 2; ++rb)
#pragma unroll
    for (int n = 0; n < 8; ++n) ao[rb][n] = (f32x4){0.f, 0.f, 0.f, 0.f};
  float llp[2] = {0.f, 0.f};

  uint4 kreg[4], vreg[4];
#pragma unroll
  for (int jj = 0; jj < 4; ++jj) {
    kreg[jj] = *(const uint4*)(Kb + (size_t)krow_[jj] * CC + kc_[jj] * 8);
    vreg[jj] = *(const uint4*)(Vtb + (size_t)drow_[jj] * TT + vc_[jj] * 8);
  }

  constexpr int NT = TT / 32;
  for (int tile = 0; tile < NT; ++tile) {
    __syncthreads();                        // prior iter's LDS reads complete
#pragma unroll
    for (int jj = 0; jj < 4; ++jj) {
      *(uint4*)((char*)kt + kdst_[jj]) = kreg[jj];
      *(uint4*)((char*)vt + vdst_[jj]) = vreg[jj];
    }
    __syncthreads();                        // tile visible
    if (tile + 1 < NT) {                    // issue next-tile loads now
      int kv0 = (tile + 1) * 32;
#pragma unroll
      for (int jj = 0; jj < 4; ++jj) {
        kreg[jj] = *(const uint4*)(Kb + (size_t)(kv0 + krow_[jj]) * CC + kc_[jj] * 8);
        vreg[jj] = *(const uint4*)(Vtb + (size_t)drow_[jj] * TT + kv0 + vc_[jj] * 8);
      }
    }

    // QK^T swapped: s[rb][n] = K-rows x Q[rb] -> D[kv][q]
    f32x4 s[2][2];
    s[0][0] = (f32x4){0,0,0,0}; s[0][1] = (f32x4){0,0,0,0};
    s[1][0] = (f32x4){0,0,0,0}; s[1][1] = (f32x4){0,0,0,0};
#pragma unroll
    for (int n = 0; n < 2; ++n) {
#pragma unroll
      for (int kk = 0; kk < 4; ++kk) {
        int row = n * 16 + lr;
        unsigned int byte = ((unsigned)(row * 256 + kk * 64 + lh * 16)) ^ (((unsigned)row & 7) << 4);
        short8 kfr = *(const short8*)((const char*)kt + byte);
        s[0][n] = __builtin_amdgcn_mfma_f32_16x16x32_bf16(kfr, qf[0][kk], s[0][n], 0, 0, 0);
        s[1][n] = __builtin_amdgcn_mfma_f32_16x16x32_bf16(kfr, qf[1][kk], s[1][n], 0, 0, 0);
      }
    }

    // p = exp(s) lane-local (q=lr, kv=16n+4lh+r); sum partials; pack -> ps
#pragma unroll
    for (int rb = 0; rb < 2; ++rb) {
      int row = rb * 16 + lr;
      unsigned int swz = (((unsigned)row >> 1) & 3) << 4;
#pragma unroll
      for (int n = 0; n < 2; ++n) {
        float p0 = __expf(s[rb][n][0]);
        float p1 = __expf(s[rb][n][1]);
        float p2 = __expf(s[rb][n][2]);
        float p3 = __expf(s[rb][n][3]);
        llp[rb] += (p0 + p1) + (p2 + p3);
        uint2 u;
        u.x = f2bf(p0) | (f2bf(p1) << 16);
        u.y = f2bf(p2) | (f2bf(p3) << 16);
        unsigned int byte = ((unsigned)(row * 64 + n * 32 + lh * 8)) ^ swz;
        *(uint2*)((char*)(&ps[w][0]) + byte) = u;
      }
    }

    // PV: ao[rb][n] += P[rb] (A-frag via ps) x V (B-frag from vt)
    short8 pf[2];
#pragma unroll
    for (int rb = 0; rb < 2; ++rb) {
      int row = rb * 16 + lr;
      unsigned int byte = ((unsigned)(row * 64 + lh * 16)) ^ ((((unsigned)row >> 1) & 3) << 4);
      pf[rb] = *(const short8*)((const char*)(&ps[w][0]) + byte);
    }
#pragma unroll
    for (int n = 0; n < 8; ++n) {
      int row = n * 16 + lr;
      unsigned int byte = ((unsigned)(row * 64 + lh * 16)) ^ ((((unsigned)row >> 1) & 3) << 4);
      short8 vfr = *(const short8*)((const char*)vt + byte);
      ao[0][n] = __builtin_amdgcn_mfma_f32_16x16x32_bf16(pf[0], vfr, ao[0][n], 0, 0, 0);
      ao[1][n] = __builtin_amdgcn_mfma_f32_16x16x32_bf16(pf[1], vfr, ao[1][n], 0, 0, 0);
    }
  }

  // epilogue: reduce denominators once, normalize, store
  unsigned short* AOb = AO + (size_t)b * TT * CC;
#pragma unroll
  for (int rb = 0; rb < 2; ++rb) {
    float s1 = llp[rb] + __shfl_xor(llp[rb], 16, 64);
    float s2 = s1 + __shfl_xor(s1, 32, 64);
    float inv = 1.0f / s2;                  // denominator for q = lr
    float ivr[4];
#pragma unroll
    for (int r = 0; r < 4; ++r) ivr[r] = __shfl(inv, lh * 4 + r, 64);
#pragma unroll
    for (int n = 0; n < 8; ++n)
#pragma unroll
      for (int r = 0; r < 4; ++r) {
        int row = q0 + w * 32 + rb * 16 + lh * 4 + r;
        int col = n * 16 + lr;
        AOb[(size_t)row * CC + col] = (unsigned short)f2bf(ao[rb][n][r] * ivr[r]);
      }
  }
}

// ---------------------------------------------------------------------------
// K4: output projection + elementwise.  out = (AO @ Wa + ba) * alpha * x
// ---------------------------------------------------------------------------
__global__ __launch_bounds__(256) void outproj_kernel(
    const unsigned short* __restrict__ AO, const unsigned short* __restrict__ Wta,
    const float* __restrict__ ba, const float* __restrict__ x,
    const float* __restrict__ alpha, float* __restrict__ out)
{
  __shared__ unsigned short as_[128 * 128];
  __shared__ unsigned short wt[128 * 128];
  const int t = threadIdx.x;
  const int tile = blockIdx.x;

#pragma unroll
  for (int i = 0; i < 8; ++i) {
    int chunk = t + 256 * i;
    int row = chunk >> 4, c16 = chunk & 15;
    uint4 d = *(const uint4*)(AO + (size_t)(tile * 128 + row) * CC + c16 * 8);
    unsigned int byte = (unsigned)(row * 256 + c16 * 16) ^ (((unsigned)row & 7) << 4);
    *(uint4*)((char*)as_ + byte) = d;
  }
#pragma unroll
  for (int i = 0; i < 8; ++i) {
    int chunk = t + 256 * i;
    int f = chunk >> 4, c16 = chunk & 15;
    uint4 d = *(const uint4*)(Wta + (size_t)f * CC + c16 * 8);
    unsigned int byte = (unsigned)(f * 256 + c16 * 16) ^ (((unsigned)f & 7) << 4);
    *(uint4*)((char*)wt + byte) = d;
  }
  __syncthreads();

  const int w = t >> 6, l = t & 63, lr = l & 15, lh = l >> 4;
  f32x4 acc[2][8];
#pragma unroll
  for (int a = 0; a < 2; ++a)
#pragma unroll
    for (int n = 0; n < 8; ++n) acc[a][n] = (f32x4){0.f, 0.f, 0.f, 0.f};

#pragma unroll
  for (int kk = 0; kk < 4; ++kk) {
    short8 a[2];
#pragma unroll
    for (int rb = 0; rb < 2; ++rb) {
      int row = w * 32 + rb * 16 + lr;
      unsigned int byte = (unsigned)(row * 256 + kk * 64 + lh * 16) ^ (((unsigned)row & 7) << 4);
      a[rb] = *(const short8*)((const char*)as_ + byte);
    }
#pragma unroll
    for (int n = 0; n < 8; ++n) {
      int row = n * 16 + lr;
      unsigned int byte = (unsigned)(row * 256 + kk * 64 + lh * 16) ^ (((unsigned)row & 7) << 4);
      short8 bfr = *(const short8*)((const char*)wt + byte);
      acc[0][n] = __builtin_amdgcn_mfma_f32_16x16x32_bf16(a[0], bfr, acc[0][n], 0, 0, 0);
      acc[1][n] = __builtin_amdgcn_mfma_f32_16x16x32_bf16(a[1], bfr, acc[1][n], 0, 0, 0);
    }
  }

  const float a0 = alpha[0];
#pragma unroll
  for (int n = 0; n < 8; ++n) {
    int col = n * 16 + lr;
    float bc = ba[col];
#pragma unroll
    for (int rb = 0; rb < 2; ++rb)
#pragma unroll
      for (int r = 0; r < 4; ++r) {
        int row = tile * 128 + w * 32 + rb * 16 + lh * 4 + r;
        size_t idx = (size_t)row * CC + col;
        out[idx] = (acc[rb][n][r] + bc) * a0 * x[idx];
      }
  }
}

// ---------------------------------------------------------------------------
extern "C" void kernel_launch(void* const* d_in, const int* in_sizes, int n_in,
                              void* d_out, int out_size, void* d_ws, size_t ws_size,
                              hipStream_t stream) {
  const float* x     = (const float*)d_in[0];
  const float* Wq    = (const float*)d_in[1];
  const float* bq    = (const float*)d_in[2];
  const float* Wk    = (const float*)d_in[3];
  const float* bk    = (const float*)d_in[4];
  const float* Wv    = (const float*)d_in[5];
  const float* bv    = (const float*)d_in[6];
  const float* Wa    = (const float*)d_in[7];
  const float* ba    = (const float*)d_in[8];
  const float* alpha = (const float*)d_in[9];
  float* out = (float*)d_out;

  char* ws = (char*)d_ws;
  const size_t MAT = (size_t)BB * TT * CC * sizeof(unsigned short); // 8 MiB
  unsigned short* Q  = (unsigned short*)(ws);
  unsigned short* K  = (unsigned short*)(ws + MAT);
  unsigned short* V  = (unsigned short*)(ws + 2 * MAT);
  unsigned short* Vt = (unsigned short*)(ws + 3 * MAT);
  unsigned short* AO = (unsigned short*)(ws + 2 * MAT);  // alias V (dead after vtrans)
  unsigned short* Wt = (unsigned short*)(ws + 4 * MAT);  // 4 x 32 KiB prepped weights

  wprep_kernel<<<dim3(4), 256, 0, stream>>>(Wq, Wk, Wv, Wa, Wt);
  qkv_kernel<<<dim3(256), 256, 0, stream>>>(x, Wt, bq, bk, bv, Q, K, V);
  vtrans_kernel<<<dim3(64, 8), 256, 0, stream>>>(V, Vt);
  flash_kernel<<<dim3(512), 128, 0, stream>>>(Q, K, Vt, AO);
  outproj_kernel<<<dim3(256), 256, 0, stream>>>(AO, Wt + 3 * (size_t)CC * CC, ba, x, alpha, out);
}

// Round 9
// 398.990 us; speedup vs baseline: 1.5539x; 1.5539x over previous
//
#include <hip/hip_runtime.h>

// GAAPAttention: q=xWq+bq, k=xWk+bk, v=xWv+bv; attn=softmax(qk^T);
// out = ((attn v)Wa + ba) * alpha * x.   B=8, T=4096, C=128, fp32 in/out.
// Flash v4: round-2's 4-wave/256-thread block shape (TLP hides latency; the
// 2-wave round-4 variant was latency-bound at 530us) + round-4's validated
// numerics: swapped QK^T (P lane-local), no-max softmax, deferred denom.
// KVBLK=64 halves barrier events vs round 2. Reg->ds_write staging with
// next-tile loads issued before compute (T14).

typedef short short8 __attribute__((ext_vector_type(8)));
typedef float f32x4 __attribute__((ext_vector_type(4)));

constexpr int BB = 8;
constexpr int TT = 4096;
constexpr int CC = 128;

__device__ inline unsigned int f2bf(float f) {
  union { float f; unsigned int u; } c; c.f = f;
  unsigned int u = c.u;
  u += 0x7fffu + ((u >> 16) & 1u);   // RTNE
  return u >> 16;
}

// ---------------------------------------------------------------------------
// K0: weight prep — transpose Wq,Wk,Wv,Wa (128x128 f32) to bf16 [f][c].
// ---------------------------------------------------------------------------
__global__ __launch_bounds__(256) void wprep_kernel(
    const float* __restrict__ Wq, const float* __restrict__ Wk,
    const float* __restrict__ Wv, const float* __restrict__ Wa,
    unsigned short* __restrict__ Wt)
{
  __shared__ unsigned short ld[128 * 136];
  const int t = threadIdx.x;
  const int m = blockIdx.x;
  const float* W = (m == 0) ? Wq : (m == 1) ? Wk : (m == 2) ? Wv : Wa;
  unsigned short* o = Wt + (size_t)m * CC * CC;
#pragma unroll
  for (int i = 0; i < 16; ++i) {
    int chunk = t + 256 * i;
    int c = chunk >> 5, f4 = (chunk & 31) * 4;
    float4 v = *(const float4*)(W + (size_t)c * CC + f4);
    uint2 u;
    u.x = f2bf(v.x) | (f2bf(v.y) << 16);
    u.y = f2bf(v.z) | (f2bf(v.w) << 16);
    *(uint2*)(ld + c * 136 + f4) = u;
  }
  __syncthreads();
#pragma unroll
  for (int i = 0; i < 16; ++i) {
    int chunk = t + 256 * i;
    int f = chunk >> 5, c4 = (chunk & 31) * 4;
    unsigned int a0 = ld[(c4 + 0) * 136 + f];
    unsigned int a1 = ld[(c4 + 1) * 136 + f];
    unsigned int a2 = ld[(c4 + 2) * 136 + f];
    unsigned int a3 = ld[(c4 + 3) * 136 + f];
    uint2 u;
    u.x = a0 | (a1 << 16);
    u.y = a2 | (a3 << 16);
    *(uint2*)(o + f * CC + c4) = u;
  }
}

// ---------------------------------------------------------------------------
// K1: fused QKV projection. grid 256, block 256 (4 waves). x staged ONCE per
// block (bf16, swizzled), then loop m=0..2 staging W^T[m] and computing.
// ---------------------------------------------------------------------------
__global__ __launch_bounds__(256) void qkv_kernel(
    const float* __restrict__ x, const unsigned short* __restrict__ Wt,
    const float* __restrict__ bq, const float* __restrict__ bk,
    const float* __restrict__ bv,
    unsigned short* __restrict__ Qo, unsigned short* __restrict__ Ko,
    unsigned short* __restrict__ Vo)
{
  __shared__ unsigned short xs[128 * 128];  // [row][c], 256B rows, ^((r&7)<<4)
  __shared__ unsigned short wt[128 * 128];  // W^T [f][c], same swizzle
  const int t = threadIdx.x;
  const int tile = blockIdx.x;

#pragma unroll
  for (int i = 0; i < 16; ++i) {
    int chunk = t + 256 * i;
    int row = chunk >> 5, c4 = chunk & 31;
    float4 v = *(const float4*)(x + (size_t)(tile * 128 + row) * CC + c4 * 4);
    uint2 u;
    u.x = f2bf(v.x) | (f2bf(v.y) << 16);
    u.y = f2bf(v.z) | (f2bf(v.w) << 16);
    unsigned int byte = (unsigned)(row * 256 + c4 * 8) ^ (((unsigned)row & 7) << 4);
    *(uint2*)((char*)xs + byte) = u;
  }

  const int w = t >> 6, l = t & 63, lr = l & 15, lh = l >> 4;

#pragma unroll
  for (int m = 0; m < 3; ++m) {
    __syncthreads();   // m=0: xs visible; m>0: prior wt reads complete
#pragma unroll
    for (int i = 0; i < 8; ++i) {
      int chunk = t + 256 * i;
      int f = chunk >> 4, c16 = chunk & 15;
      uint4 d = *(const uint4*)(Wt + (size_t)m * CC * CC + (size_t)f * CC + c16 * 8);
      unsigned int byte = (unsigned)(f * 256 + c16 * 16) ^ (((unsigned)f & 7) << 4);
      *(uint4*)((char*)wt + byte) = d;
    }
    __syncthreads();

    const float* bias = (m == 0) ? bq : (m == 1) ? bk : bv;
    unsigned short* out = (m == 0) ? Qo : (m == 1) ? Ko : Vo;

    f32x4 acc[2][8];
#pragma unroll
    for (int a = 0; a < 2; ++a)
#pragma unroll
      for (int n = 0; n < 8; ++n) acc[a][n] = (f32x4){0.f, 0.f, 0.f, 0.f};

#pragma unroll
    for (int kk = 0; kk < 4; ++kk) {
      short8 a[2];
#pragma unroll
      for (int rb = 0; rb < 2; ++rb) {
        int row = w * 32 + rb * 16 + lr;
        unsigned int byte = (unsigned)(row * 256 + kk * 64 + lh * 16) ^ (((unsigned)row & 7) << 4);
        a[rb] = *(const short8*)((const char*)xs + byte);
      }
#pragma unroll
      for (int n = 0; n < 8; ++n) {
        int row = n * 16 + lr;
        unsigned int byte = (unsigned)(row * 256 + kk * 64 + lh * 16) ^ (((unsigned)row & 7) << 4);
        short8 bfr = *(const short8*)((const char*)wt + byte);
        acc[0][n] = __builtin_amdgcn_mfma_f32_16x16x32_bf16(a[0], bfr, acc[0][n], 0, 0, 0);
        acc[1][n] = __builtin_amdgcn_mfma_f32_16x16x32_bf16(a[1], bfr, acc[1][n], 0, 0, 0);
      }
    }
#pragma unroll
    for (int n = 0; n < 8; ++n) {
      int col = n * 16 + lr;
      float bc = bias[col];
#pragma unroll
      for (int rb = 0; rb < 2; ++rb)
#pragma unroll
        for (int r = 0; r < 4; ++r) {
          int row = tile * 128 + w * 32 + rb * 16 + lh * 4 + r;
          out[(size_t)row * CC + col] = (unsigned short)f2bf(acc[rb][n][r] + bc);
        }
    }
  }
}

// ---------------------------------------------------------------------------
// K2: V transpose  V[b][t][d] -> Vt[b][d][t].
// ---------------------------------------------------------------------------
__global__ __launch_bounds__(256) void vtrans_kernel(
    const unsigned short* __restrict__ V, unsigned short* __restrict__ Vt)
{
  __shared__ unsigned short tile[64 * 136];
  const int t = threadIdx.x;
  const int b = blockIdx.y;
  const int kv0 = blockIdx.x * 64;
  const unsigned short* Vb = V + (size_t)b * TT * CC;
  unsigned short* Vtb = Vt + (size_t)b * TT * CC;
#pragma unroll
  for (int i = 0; i < 4; ++i) {
    int chunk = t + 256 * i;
    int row = chunk >> 4, c16 = chunk & 15;
    uint4 d = *(const uint4*)(Vb + (size_t)(kv0 + row) * CC + c16 * 8);
    *(uint4*)(tile + row * 136 + c16 * 8) = d;
  }
  __syncthreads();
#pragma unroll
  for (int i = 0; i < 4; ++i) {
    int chunk = t + 256 * i;
    int dd = chunk >> 3, kc = chunk & 7;
    unsigned short tmp[8];
#pragma unroll
    for (int j = 0; j < 8; ++j) tmp[j] = tile[(kc * 8 + j) * 136 + dd];
    uint4 u;
    u.x = (unsigned)tmp[0] | ((unsigned)tmp[1] << 16);
    u.y = (unsigned)tmp[2] | ((unsigned)tmp[3] << 16);
    u.z = (unsigned)tmp[4] | ((unsigned)tmp[5] << 16);
    u.w = (unsigned)tmp[6] | ((unsigned)tmp[7] << 16);
    *(uint4*)(Vtb + (size_t)dd * TT + kv0 + kc * 8) = u;
  }
}

// ---------------------------------------------------------------------------
// K3: flash attention v4.  grid 512 (b = bid&7), block 256 = 4 waves x 16
// q-rows; KVBLK = 64.  Swapped QK^T: s = mfma(K, Q) so lane owns q = lane&15;
// p = exp(s) lane-local; denominator per-lane partials, one reduce at end.
// Staging: reg->ds_write single buffer, 2 barriers/iter; next-tile loads
// issued before compute (latency hidden by 8 waves/CU TLP + MFMA).
// ---------------------------------------------------------------------------
__global__ __launch_bounds__(256) void flash_kernel(
    const unsigned short* __restrict__ Q,
    const unsigned short* __restrict__ K,
    const unsigned short* __restrict__ Vt,
    unsigned short* __restrict__ AO)
{
  __shared__ unsigned short kt[64 * 128];   // [kv][d] 256B rows, ^((r&7)<<4)
  __shared__ unsigned short vt[128 * 64];   // [d][kv] 128B rows, ^((r&7)<<4)
  __shared__ unsigned short ps[4][16 * 64]; // per-wave P[q][kv], 128B rows, same swz
  const int t = threadIdx.x, w = t >> 6, l = t & 63, lr = l & 15, lh = l >> 4;
  const int bid = blockIdx.x;
  const int b = bid & 7;
  const int q0 = (bid >> 3) * 64;
  const unsigned short* Qb  = Q  + (size_t)b * TT * CC;
  const unsigned short* Kb  = K  + (size_t)b * TT * CC;
  const unsigned short* Vtb = Vt + (size_t)b * TT * CC;

  // Q B-fragments: col = q = lr (rows q0 + w*16 + lr), k = kk*32 + lh*8 + j
  short8 qf[4];
  {
    int qrow = q0 + w * 16 + lr;
#pragma unroll
    for (int kk = 0; kk < 4; ++kk)
      qf[kk] = *(const short8*)(Qb + (size_t)qrow * CC + kk * 32 + lh * 8);
  }

  // staging geometry: 4 chunks of 16B each for K (16KB) and V^T (16KB)
  int krow_[4], kc_[4], drow_[4], vc_[4];
  unsigned int kdst_[4], vdst_[4];
#pragma unroll
  for (int jj = 0; jj < 4; ++jj) {
    int chunk = jj * 256 + t;               // 0..1023
    krow_[jj] = chunk >> 4; kc_[jj] = chunk & 15;            // 64 rows x 16
    kdst_[jj] = ((unsigned)(krow_[jj] * 256 + kc_[jj] * 16)) ^ (((unsigned)krow_[jj] & 7) << 4);
    drow_[jj] = chunk >> 3; vc_[jj] = chunk & 7;             // 128 rows x 8
    vdst_[jj] = ((unsigned)(drow_[jj] * 128 + vc_[jj] * 16)) ^ (((unsigned)drow_[jj] & 7) << 4);
  }

  f32x4 ao[8];
#pragma unroll
  for (int n = 0; n < 8; ++n) ao[n] = (f32x4){0.f, 0.f, 0.f, 0.f};
  float llp = 0.f;

  uint4 kreg[4], vreg[4];
#pragma unroll
  for (int jj = 0; jj < 4; ++jj) {
    kreg[jj] = *(const uint4*)(Kb + (size_t)krow_[jj] * CC + kc_[jj] * 8);
    vreg[jj] = *(const uint4*)(Vtb + (size_t)drow_[jj] * TT + vc_[jj] * 8);
  }

  constexpr int NT = TT / 64;
  for (int tile = 0; tile < NT; ++tile) {
    __syncthreads();                        // prior iter's LDS reads complete
#pragma unroll
    for (int jj = 0; jj < 4; ++jj) {
      *(uint4*)((char*)kt + kdst_[jj]) = kreg[jj];
      *(uint4*)((char*)vt + vdst_[jj]) = vreg[jj];
    }
    __syncthreads();                        // tile visible
    if (tile + 1 < NT) {                    // issue next-tile loads now
      int kv0 = (tile + 1) * 64;
#pragma unroll
      for (int jj = 0; jj < 4; ++jj) {
        kreg[jj] = *(const uint4*)(Kb + (size_t)(kv0 + krow_[jj]) * CC + kc_[jj] * 8);
        vreg[jj] = *(const uint4*)(Vtb + (size_t)drow_[jj] * TT + kv0 + vc_[jj] * 8);
      }
    }

    // QK^T swapped: s[n] = K-rows[16n..] x Q -> D[kv][q], q = lane&15
    f32x4 s[4];
#pragma unroll
    for (int n = 0; n < 4; ++n) s[n] = (f32x4){0.f, 0.f, 0.f, 0.f};
#pragma unroll
    for (int n = 0; n < 4; ++n) {
#pragma unroll
      for (int kk = 0; kk < 4; ++kk) {
        int row = n * 16 + lr;
        unsigned int byte = ((unsigned)(row * 256 + kk * 64 + lh * 16)) ^ (((unsigned)row & 7) << 4);
        short8 kfr = *(const short8*)((const char*)kt + byte);
        s[n] = __builtin_amdgcn_mfma_f32_16x16x32_bf16(kfr, qf[kk], s[n], 0, 0, 0);
      }
    }

    // p = exp(s) lane-local (q = lr, kv = 16n + 4lh + r); pack -> ps
    unsigned int pswz = ((unsigned)lr & 7) << 4;
#pragma unroll
    for (int n = 0; n < 4; ++n) {
      float p0 = __expf(s[n][0]);
      float p1 = __expf(s[n][1]);
      float p2 = __expf(s[n][2]);
      float p3 = __expf(s[n][3]);
      llp += (p0 + p1) + (p2 + p3);
      uint2 u;
      u.x = f2bf(p0) | (f2bf(p1) << 16);
      u.y = f2bf(p2) | (f2bf(p3) << 16);
      unsigned int byte = ((unsigned)(lr * 128 + n * 32 + lh * 8)) ^ pswz;
      *(uint2*)((char*)(&ps[w][0]) + byte) = u;
    }

    // PV: ao[n] += P (A-frag, k = kk2*32+lh*8+j) x V^T (B-frag)
    short8 pf[2];
#pragma unroll
    for (int kk2 = 0; kk2 < 2; ++kk2) {
      unsigned int byte = ((unsigned)(lr * 128 + kk2 * 64 + lh * 16)) ^ pswz;
      pf[kk2] = *(const short8*)((const char*)(&ps[w][0]) + byte);
    }
#pragma unroll
    for (int n = 0; n < 8; ++n) {
#pragma unroll
      for (int kk2 = 0; kk2 < 2; ++kk2) {
        int row = n * 16 + lr;
        unsigned int byte = ((unsigned)(row * 128 + kk2 * 64 + lh * 16)) ^ (((unsigned)row & 7) << 4);
        short8 vfr = *(const short8*)((const char*)vt + byte);
        ao[n] = __builtin_amdgcn_mfma_f32_16x16x32_bf16(pf[kk2], vfr, ao[n], 0, 0, 0);
      }
    }
  }

  // epilogue: reduce denominators once, normalize, store
  unsigned short* AOb = AO + (size_t)b * TT * CC;
  float s1 = llp + __shfl_xor(llp, 16, 64);
  float s2 = s1 + __shfl_xor(s1, 32, 64);
  float inv = 1.0f / s2;                    // denominator for q = lr
  float ivr[4];
#pragma unroll
  for (int r = 0; r < 4; ++r) ivr[r] = __shfl(inv, lh * 4 + r, 64);
#pragma unroll
  for (int n = 0; n < 8; ++n)
#pragma unroll
    for (int r = 0; r < 4; ++r) {
      int row = q0 + w * 16 + lh * 4 + r;
      int col = n * 16 + lr;
      AOb[(size_t)row * CC + col] = (unsigned short)f2bf(ao[n][r] * ivr[r]);
    }
}

// ---------------------------------------------------------------------------
// K4: output projection + elementwise.  out = (AO @ Wa + ba) * alpha * x
// ---------------------------------------------------------------------------
__global__ __launch_bounds__(256) void outproj_kernel(
    const unsigned short* __restrict__ AO, const unsigned short* __restrict__ Wta,
    const float* __restrict__ ba, const float* __restrict__ x,
    const float* __restrict__ alpha, float* __restrict__ out)
{
  __shared__ unsigned short as_[128 * 128];
  __shared__ unsigned short wt[128 * 128];
  const int t = threadIdx.x;
  const int tile = blockIdx.x;

#pragma unroll
  for (int i = 0; i < 8; ++i) {
    int chunk = t + 256 * i;
    int row = chunk >> 4, c16 = chunk & 15;
    uint4 d = *(const uint4*)(AO + (size_t)(tile * 128 + row) * CC + c16 * 8);
    unsigned int byte = (unsigned)(row * 256 + c16 * 16) ^ (((unsigned)row & 7) << 4);
    *(uint4*)((char*)as_ + byte) = d;
  }
#pragma unroll
  for (int i = 0; i < 8; ++i) {
    int chunk = t + 256 * i;
    int f = chunk >> 4, c16 = chunk & 15;
    uint4 d = *(const uint4*)(Wta + (size_t)f * CC + c16 * 8);
    unsigned int byte = (unsigned)(f * 256 + c16 * 16) ^ (((unsigned)f & 7) << 4);
    *(uint4*)((char*)wt + byte) = d;
  }
  __syncthreads();

  const int w = t >> 6, l = t & 63, lr = l & 15, lh = l >> 4;
  f32x4 acc[2][8];
#pragma unroll
  for (int a = 0; a < 2; ++a)
#pragma unroll
    for (int n = 0; n < 8; ++n) acc[a][n] = (f32x4){0.f, 0.f, 0.f, 0.f};

#pragma unroll
  for (int kk = 0; kk < 4; ++kk) {
    short8 a[2];
#pragma unroll
    for (int rb = 0; rb < 2; ++rb) {
      int row = w * 32 + rb * 16 + lr;
      unsigned int byte = (unsigned)(row * 256 + kk * 64 + lh * 16) ^ (((unsigned)row & 7) << 4);
      a[rb] = *(const short8*)((const char*)as_ + byte);
    }
#pragma unroll
    for (int n = 0; n < 8; ++n) {
      int row = n * 16 + lr;
      unsigned int byte = (unsigned)(row * 256 + kk * 64 + lh * 16) ^ (((unsigned)row & 7) << 4);
      short8 bfr = *(const short8*)((const char*)wt + byte);
      acc[0][n] = __builtin_amdgcn_mfma_f32_16x16x32_bf16(a[0], bfr, acc[0][n], 0, 0, 0);
      acc[1][n] = __builtin_amdgcn_mfma_f32_16x16x32_bf16(a[1], bfr, acc[1][n], 0, 0, 0);
    }
  }

  const float a0 = alpha[0];
#pragma unroll
  for (int n = 0; n < 8; ++n) {
    int col = n * 16 + lr;
    float bc = ba[col];
#pragma unroll
    for (int rb = 0; rb < 2; ++rb)
#pragma unroll
      for (int r = 0; r < 4; ++r) {
        int row = tile * 128 + w * 32 + rb * 16 + lh * 4 + r;
        size_t idx = (size_t)row * CC + col;
        out[idx] = (acc[rb][n][r] + bc) * a0 * x[idx];
      }
  }
}

// ---------------------------------------------------------------------------
extern "C" void kernel_launch(void* const* d_in, const int* in_sizes, int n_in,
                              void* d_out, int out_size, void* d_ws, size_t ws_size,
                              hipStream_t stream) {
  const float* x     = (const float*)d_in[0];
  const float* Wq    = (const float*)d_in[1];
  const float* bq    = (const float*)d_in[2];
  const float* Wk    = (const float*)d_in[3];
  const float* bk    = (const float*)d_in[4];
  const float* Wv    = (const float*)d_in[5];
  const float* bv    = (const float*)d_in[6];
  const float* Wa    = (const float*)d_in[7];
  const float* ba    = (const float*)d_in[8];
  const float* alpha = (const float*)d_in[9];
  float* out = (float*)d_out;

  char* ws = (char*)d_ws;
  const size_t MAT = (size_t)BB * TT * CC * sizeof(unsigned short); // 8 MiB
  unsigned short* Q  = (unsigned short*)(ws);
  unsigned short* K  = (unsigned short*)(ws + MAT);
  unsigned short* V  = (unsigned short*)(ws + 2 * MAT);
  unsigned short* Vt = (unsigned short*)(ws + 3 * MAT);
  unsigned short* AO = (unsigned short*)(ws + 2 * MAT);  // alias V (dead after vtrans)
  unsigned short* Wt = (unsigned short*)(ws + 4 * MAT);  // 4 x 32 KiB prepped weights

  wprep_kernel<<<dim3(4), 256, 0, stream>>>(Wq, Wk, Wv, Wa, Wt);
  qkv_kernel<<<dim3(256), 256, 0, stream>>>(x, Wt, bq, bk, bv, Q, K, V);
  vtrans_kernel<<<dim3(64, 8), 256, 0, stream>>>(V, Vt);
  flash_kernel<<<dim3(512), 256, 0, stream>>>(Q, K, Vt, AO);
  outproj_kernel<<<dim3(256), 256, 0, stream>>>(AO, Wt + 3 * (size_t)CC * CC, ba, x, alpha, out);
}

// Round 10
// 216.351 us; speedup vs baseline: 2.8657x; 1.8442x over previous
//
#include <hip/hip_runtime.h>

// GAAPAttention: q=xWq+bq, k=xWk+bk, v=xWv+bv; attn=softmax(qk^T);
// out = ((attn v)Wa + ba) * alpha * x.   B=8, T=4096, C=128, fp32 in/out.
// Flash v5 = v4 + spill fix. Round-9 counters showed WRITE_SIZE 567MB/dispatch
// (vs 8MB output) = kreg/vreg (64B/thread) spilled to scratch every iter at
// VGPR_Count=84. Fix: __launch_bounds__(256,2) (LDS limits us to 2 blocks/CU
// anyway -> ~256 VGPR budget) + named staging registers (no spillable arrays).

typedef short short8 __attribute__((ext_vector_type(8)));
typedef float f32x4 __attribute__((ext_vector_type(4)));

constexpr int BB = 8;
constexpr int TT = 4096;
constexpr int CC = 128;

__device__ inline unsigned int f2bf(float f) {
  union { float f; unsigned int u; } c; c.f = f;
  unsigned int u = c.u;
  u += 0x7fffu + ((u >> 16) & 1u);   // RTNE
  return u >> 16;
}

// ---------------------------------------------------------------------------
// K0: weight prep — transpose Wq,Wk,Wv,Wa (128x128 f32) to bf16 [f][c].
// ---------------------------------------------------------------------------
__global__ __launch_bounds__(256) void wprep_kernel(
    const float* __restrict__ Wq, const float* __restrict__ Wk,
    const float* __restrict__ Wv, const float* __restrict__ Wa,
    unsigned short* __restrict__ Wt)
{
  __shared__ unsigned short ld[128 * 136];
  const int t = threadIdx.x;
  const int m = blockIdx.x;
  const float* W = (m == 0) ? Wq : (m == 1) ? Wk : (m == 2) ? Wv : Wa;
  unsigned short* o = Wt + (size_t)m * CC * CC;
#pragma unroll
  for (int i = 0; i < 16; ++i) {
    int chunk = t + 256 * i;
    int c = chunk >> 5, f4 = (chunk & 31) * 4;
    float4 v = *(const float4*)(W + (size_t)c * CC + f4);
    uint2 u;
    u.x = f2bf(v.x) | (f2bf(v.y) << 16);
    u.y = f2bf(v.z) | (f2bf(v.w) << 16);
    *(uint2*)(ld + c * 136 + f4) = u;
  }
  __syncthreads();
#pragma unroll
  for (int i = 0; i < 16; ++i) {
    int chunk = t + 256 * i;
    int f = chunk >> 5, c4 = (chunk & 31) * 4;
    unsigned int a0 = ld[(c4 + 0) * 136 + f];
    unsigned int a1 = ld[(c4 + 1) * 136 + f];
    unsigned int a2 = ld[(c4 + 2) * 136 + f];
    unsigned int a3 = ld[(c4 + 3) * 136 + f];
    uint2 u;
    u.x = a0 | (a1 << 16);
    u.y = a2 | (a3 << 16);
    *(uint2*)(o + f * CC + c4) = u;
  }
}

// ---------------------------------------------------------------------------
// K1: fused QKV projection. grid 256, block 256 (4 waves). x staged ONCE per
// block (bf16, swizzled), then loop m=0..2 staging W^T[m] and computing.
// ---------------------------------------------------------------------------
__global__ __launch_bounds__(256) void qkv_kernel(
    const float* __restrict__ x, const unsigned short* __restrict__ Wt,
    const float* __restrict__ bq, const float* __restrict__ bk,
    const float* __restrict__ bv,
    unsigned short* __restrict__ Qo, unsigned short* __restrict__ Ko,
    unsigned short* __restrict__ Vo)
{
  __shared__ unsigned short xs[128 * 128];  // [row][c], 256B rows, ^((r&7)<<4)
  __shared__ unsigned short wt[128 * 128];  // W^T [f][c], same swizzle
  const int t = threadIdx.x;
  const int tile = blockIdx.x;

#pragma unroll
  for (int i = 0; i < 16; ++i) {
    int chunk = t + 256 * i;
    int row = chunk >> 5, c4 = chunk & 31;
    float4 v = *(const float4*)(x + (size_t)(tile * 128 + row) * CC + c4 * 4);
    uint2 u;
    u.x = f2bf(v.x) | (f2bf(v.y) << 16);
    u.y = f2bf(v.z) | (f2bf(v.w) << 16);
    unsigned int byte = (unsigned)(row * 256 + c4 * 8) ^ (((unsigned)row & 7) << 4);
    *(uint2*)((char*)xs + byte) = u;
  }

  const int w = t >> 6, l = t & 63, lr = l & 15, lh = l >> 4;

#pragma unroll
  for (int m = 0; m < 3; ++m) {
    __syncthreads();   // m=0: xs visible; m>0: prior wt reads complete
#pragma unroll
    for (int i = 0; i < 8; ++i) {
      int chunk = t + 256 * i;
      int f = chunk >> 4, c16 = chunk & 15;
      uint4 d = *(const uint4*)(Wt + (size_t)m * CC * CC + (size_t)f * CC + c16 * 8);
      unsigned int byte = (unsigned)(f * 256 + c16 * 16) ^ (((unsigned)f & 7) << 4);
      *(uint4*)((char*)wt + byte) = d;
    }
    __syncthreads();

    const float* bias = (m == 0) ? bq : (m == 1) ? bk : bv;
    unsigned short* out = (m == 0) ? Qo : (m == 1) ? Ko : Vo;

    f32x4 acc[2][8];
#pragma unroll
    for (int a = 0; a < 2; ++a)
#pragma unroll
      for (int n = 0; n < 8; ++n) acc[a][n] = (f32x4){0.f, 0.f, 0.f, 0.f};

#pragma unroll
    for (int kk = 0; kk < 4; ++kk) {
      short8 a[2];
#pragma unroll
      for (int rb = 0; rb < 2; ++rb) {
        int row = w * 32 + rb * 16 + lr;
        unsigned int byte = (unsigned)(row * 256 + kk * 64 + lh * 16) ^ (((unsigned)row & 7) << 4);
        a[rb] = *(const short8*)((const char*)xs + byte);
      }
#pragma unroll
      for (int n = 0; n < 8; ++n) {
        int row = n * 16 + lr;
        unsigned int byte = (unsigned)(row * 256 + kk * 64 + lh * 16) ^ (((unsigned)row & 7) << 4);
        short8 bfr = *(const short8*)((const char*)wt + byte);
        acc[0][n] = __builtin_amdgcn_mfma_f32_16x16x32_bf16(a[0], bfr, acc[0][n], 0, 0, 0);
        acc[1][n] = __builtin_amdgcn_mfma_f32_16x16x32_bf16(a[1], bfr, acc[1][n], 0, 0, 0);
      }
    }
#pragma unroll
    for (int n = 0; n < 8; ++n) {
      int col = n * 16 + lr;
      float bc = bias[col];
#pragma unroll
      for (int rb = 0; rb < 2; ++rb)
#pragma unroll
        for (int r = 0; r < 4; ++r) {
          int row = tile * 128 + w * 32 + rb * 16 + lh * 4 + r;
          out[(size_t)row * CC + col] = (unsigned short)f2bf(acc[rb][n][r] + bc);
        }
    }
  }
}

// ---------------------------------------------------------------------------
// K2: V transpose  V[b][t][d] -> Vt[b][d][t].
// ---------------------------------------------------------------------------
__global__ __launch_bounds__(256) void vtrans_kernel(
    const unsigned short* __restrict__ V, unsigned short* __restrict__ Vt)
{
  __shared__ unsigned short tile[64 * 136];
  const int t = threadIdx.x;
  const int b = blockIdx.y;
  const int kv0 = blockIdx.x * 64;
  const unsigned short* Vb = V + (size_t)b * TT * CC;
  unsigned short* Vtb = Vt + (size_t)b * TT * CC;
#pragma unroll
  for (int i = 0; i < 4; ++i) {
    int chunk = t + 256 * i;
    int row = chunk >> 4, c16 = chunk & 15;
    uint4 d = *(const uint4*)(Vb + (size_t)(kv0 + row) * CC + c16 * 8);
    *(uint4*)(tile + row * 136 + c16 * 8) = d;
  }
  __syncthreads();
#pragma unroll
  for (int i = 0; i < 4; ++i) {
    int chunk = t + 256 * i;
    int dd = chunk >> 3, kc = chunk & 7;
    unsigned short tmp[8];
#pragma unroll
    for (int j = 0; j < 8; ++j) tmp[j] = tile[(kc * 8 + j) * 136 + dd];
    uint4 u;
    u.x = (unsigned)tmp[0] | ((unsigned)tmp[1] << 16);
    u.y = (unsigned)tmp[2] | ((unsigned)tmp[3] << 16);
    u.z = (unsigned)tmp[4] | ((unsigned)tmp[5] << 16);
    u.w = (unsigned)tmp[6] | ((unsigned)tmp[7] << 16);
    *(uint4*)(Vtb + (size_t)dd * TT + kv0 + kc * 8) = u;
  }
}

// ---------------------------------------------------------------------------
// K3: flash attention v5.  grid 512 (b = bid&7), block 256 = 4 waves x 16
// q-rows; KVBLK = 64.  Swapped QK^T: s = mfma(K, Q) so lane owns q = lane&15;
// p = exp(s) lane-local; denominator per-lane partials, one reduce at end.
// Staging payload in NAMED registers (k0..k3, v0..v3) + launch_bounds(256,2):
// LDS (40KB) caps us at 2 blocks/CU anyway, so give the allocator the full
// ~256-VGPR budget and forbid the round-9 scratch spill (567MB/dispatch HBM
// writes = 64B/thread/iter spill-store of the old kreg[]/vreg[] arrays).
// ---------------------------------------------------------------------------
__global__ __launch_bounds__(256, 2) void flash_kernel(
    const unsigned short* __restrict__ Q,
    const unsigned short* __restrict__ K,
    const unsigned short* __restrict__ Vt,
    unsigned short* __restrict__ AO)
{
  __shared__ unsigned short kt[64 * 128];   // [kv][d] 256B rows, ^((r&7)<<4)
  __shared__ unsigned short vt[128 * 64];   // [d][kv] 128B rows, ^((r&7)<<4)
  __shared__ unsigned short ps[4][16 * 64]; // per-wave P[q][kv], 128B rows, same swz
  const int t = threadIdx.x, w = t >> 6, l = t & 63, lr = l & 15, lh = l >> 4;
  const int bid = blockIdx.x;
  const int b = bid & 7;
  const int q0 = (bid >> 3) * 64;
  const unsigned short* Qb  = Q  + (size_t)b * TT * CC;
  const unsigned short* Kb  = K  + (size_t)b * TT * CC;
  const unsigned short* Vtb = Vt + (size_t)b * TT * CC;

  // Q B-fragments: col = q = lr (rows q0 + w*16 + lr), k = kk*32 + lh*8 + j
  short8 qf[4];
  {
    int qrow = q0 + w * 16 + lr;
#pragma unroll
    for (int kk = 0; kk < 4; ++kk)
      qf[kk] = *(const short8*)(Qb + (size_t)qrow * CC + kk * 32 + lh * 8);
  }

  // staging geometry: 4 chunks of 16B each for K (16KB) and V^T (16KB);
  // chunk jj covers 256 threads -> chunk index jj*256 + t.
  const int c0 = t, c1 = t + 256, c2 = t + 512, c3 = t + 768;
  const int kr0 = c0 >> 4, kr1 = c1 >> 4, kr2 = c2 >> 4, kr3 = c3 >> 4;
  const int kb0 = (c0 & 15) * 16, kb1 = (c1 & 15) * 16,
            kb2 = (c2 & 15) * 16, kb3 = (c3 & 15) * 16;
  const unsigned int kd0 = ((unsigned)(kr0 * 256 + kb0)) ^ (((unsigned)kr0 & 7) << 4);
  const unsigned int kd1 = ((unsigned)(kr1 * 256 + kb1)) ^ (((unsigned)kr1 & 7) << 4);
  const unsigned int kd2 = ((unsigned)(kr2 * 256 + kb2)) ^ (((unsigned)kr2 & 7) << 4);
  const unsigned int kd3 = ((unsigned)(kr3 * 256 + kb3)) ^ (((unsigned)kr3 & 7) << 4);
  const int dr0 = c0 >> 3, dr1 = c1 >> 3, dr2 = c2 >> 3, dr3 = c3 >> 3;
  const int vb0 = (c0 & 7) * 16, vb1 = (c1 & 7) * 16,
            vb2 = (c2 & 7) * 16, vb3 = (c3 & 7) * 16;
  const unsigned int vd0 = ((unsigned)(dr0 * 128 + vb0)) ^ (((unsigned)dr0 & 7) << 4);
  const unsigned int vd1 = ((unsigned)(dr1 * 128 + vb1)) ^ (((unsigned)dr1 & 7) << 4);
  const unsigned int vd2 = ((unsigned)(dr2 * 128 + vb2)) ^ (((unsigned)dr2 & 7) << 4);
  const unsigned int vd3 = ((unsigned)(dr3 * 128 + vb3)) ^ (((unsigned)dr3 & 7) << 4);

  f32x4 ao[8];
#pragma unroll
  for (int n = 0; n < 8; ++n) ao[n] = (f32x4){0.f, 0.f, 0.f, 0.f};
  float llp = 0.f;

  // named staging registers (no spillable aggregates)
  uint4 k0 = *(const uint4*)(Kb + (size_t)kr0 * CC + (kb0 >> 1));
  uint4 k1 = *(const uint4*)(Kb + (size_t)kr1 * CC + (kb1 >> 1));
  uint4 k2 = *(const uint4*)(Kb + (size_t)kr2 * CC + (kb2 >> 1));
  uint4 k3 = *(const uint4*)(Kb + (size_t)kr3 * CC + (kb3 >> 1));
  uint4 v0 = *(const uint4*)(Vtb + (size_t)dr0 * TT + (vb0 >> 1));
  uint4 v1 = *(const uint4*)(Vtb + (size_t)dr1 * TT + (vb1 >> 1));
  uint4 v2 = *(const uint4*)(Vtb + (size_t)dr2 * TT + (vb2 >> 1));
  uint4 v3 = *(const uint4*)(Vtb + (size_t)dr3 * TT + (vb3 >> 1));

  constexpr int NT = TT / 64;
  for (int tile = 0; tile < NT; ++tile) {
    __syncthreads();                        // prior iter's LDS reads complete
    *(uint4*)((char*)kt + kd0) = k0;
    *(uint4*)((char*)kt + kd1) = k1;
    *(uint4*)((char*)kt + kd2) = k2;
    *(uint4*)((char*)kt + kd3) = k3;
    *(uint4*)((char*)vt + vd0) = v0;
    *(uint4*)((char*)vt + vd1) = v1;
    *(uint4*)((char*)vt + vd2) = v2;
    *(uint4*)((char*)vt + vd3) = v3;
    __syncthreads();                        // tile visible
    if (tile + 1 < NT) {                    // issue next-tile loads now
      int kv0 = (tile + 1) * 64;
      k0 = *(const uint4*)(Kb + (size_t)(kv0 + kr0) * CC + (kb0 >> 1));
      k1 = *(const uint4*)(Kb + (size_t)(kv0 + kr1) * CC + (kb1 >> 1));
      k2 = *(const uint4*)(Kb + (size_t)(kv0 + kr2) * CC + (kb2 >> 1));
      k3 = *(const uint4*)(Kb + (size_t)(kv0 + kr3) * CC + (kb3 >> 1));
      v0 = *(const uint4*)(Vtb + (size_t)dr0 * TT + kv0 + (vb0 >> 1));
      v1 = *(const uint4*)(Vtb + (size_t)dr1 * TT + kv0 + (vb1 >> 1));
      v2 = *(const uint4*)(Vtb + (size_t)dr2 * TT + kv0 + (vb2 >> 1));
      v3 = *(const uint4*)(Vtb + (size_t)dr3 * TT + kv0 + (vb3 >> 1));
    }

    // QK^T swapped: s[n] = K-rows[16n..] x Q -> D[kv][q], q = lane&15
    f32x4 s[4];
#pragma unroll
    for (int n = 0; n < 4; ++n) s[n] = (f32x4){0.f, 0.f, 0.f, 0.f};
#pragma unroll
    for (int n = 0; n < 4; ++n) {
#pragma unroll
      for (int kk = 0; kk < 4; ++kk) {
        int row = n * 16 + lr;
        unsigned int byte = ((unsigned)(row * 256 + kk * 64 + lh * 16)) ^ (((unsigned)row & 7) << 4);
        short8 kfr = *(const short8*)((const char*)kt + byte);
        s[n] = __builtin_amdgcn_mfma_f32_16x16x32_bf16(kfr, qf[kk], s[n], 0, 0, 0);
      }
    }

    // p = exp(s) lane-local (q = lr, kv = 16n + 4lh + r); pack -> ps
    unsigned int pswz = ((unsigned)lr & 7) << 4;
#pragma unroll
    for (int n = 0; n < 4; ++n) {
      float p0 = __expf(s[n][0]);
      float p1 = __expf(s[n][1]);
      float p2 = __expf(s[n][2]);
      float p3 = __expf(s[n][3]);
      llp += (p0 + p1) + (p2 + p3);
      uint2 u;
      u.x = f2bf(p0) | (f2bf(p1) << 16);
      u.y = f2bf(p2) | (f2bf(p3) << 16);
      unsigned int byte = ((unsigned)(lr * 128 + n * 32 + lh * 8)) ^ pswz;
      *(uint2*)((char*)(&ps[w][0]) + byte) = u;
    }

    // PV: ao[n] += P (A-frag, k = kk2*32+lh*8+j) x V^T (B-frag)
    short8 pf[2];
#pragma unroll
    for (int kk2 = 0; kk2 < 2; ++kk2) {
      unsigned int byte = ((unsigned)(lr * 128 + kk2 * 64 + lh * 16)) ^ pswz;
      pf[kk2] = *(const short8*)((const char*)(&ps[w][0]) + byte);
    }
#pragma unroll
    for (int n = 0; n < 8; ++n) {
#pragma unroll
      for (int kk2 = 0; kk2 < 2; ++kk2) {
        int row = n * 16 + lr;
        unsigned int byte = ((unsigned)(row * 128 + kk2 * 64 + lh * 16)) ^ (((unsigned)row & 7) << 4);
        short8 vfr = *(const short8*)((const char*)vt + byte);
        ao[n] = __builtin_amdgcn_mfma_f32_16x16x32_bf16(pf[kk2], vfr, ao[n], 0, 0, 0);
      }
    }
  }

  // epilogue: reduce denominators once, normalize, store
  unsigned short* AOb = AO + (size_t)b * TT * CC;
  float s1 = llp + __shfl_xor(llp, 16, 64);
  float s2 = s1 + __shfl_xor(s1, 32, 64);
  float inv = 1.0f / s2;                    // denominator for q = lr
  float ivr[4];
#pragma unroll
  for (int r = 0; r < 4; ++r) ivr[r] = __shfl(inv, lh * 4 + r, 64);
#pragma unroll
  for (int n = 0; n < 8; ++n)
#pragma unroll
    for (int r = 0; r < 4; ++r) {
      int row = q0 + w * 16 + lh * 4 + r;
      int col = n * 16 + lr;
      AOb[(size_t)row * CC + col] = (unsigned short)f2bf(ao[n][r] * ivr[r]);
    }
}

// ---------------------------------------------------------------------------
// K4: output projection + elementwise.  out = (AO @ Wa + ba) * alpha * x
// ---------------------------------------------------------------------------
__global__ __launch_bounds__(256) void outproj_kernel(
    const unsigned short* __restrict__ AO, const unsigned short* __restrict__ Wta,
    const float* __restrict__ ba, const float* __restrict__ x,
    const float* __restrict__ alpha, float* __restrict__ out)
{
  __shared__ unsigned short as_[128 * 128];
  __shared__ unsigned short wt[128 * 128];
  const int t = threadIdx.x;
  const int tile = blockIdx.x;

#pragma unroll
  for (int i = 0; i < 8; ++i) {
    int chunk = t + 256 * i;
    int row = chunk >> 4, c16 = chunk & 15;
    uint4 d = *(const uint4*)(AO + (size_t)(tile * 128 + row) * CC + c16 * 8);
    unsigned int byte = (unsigned)(row * 256 + c16 * 16) ^ (((unsigned)row & 7) << 4);
    *(uint4*)((char*)as_ + byte) = d;
  }
#pragma unroll
  for (int i = 0; i < 8; ++i) {
    int chunk = t + 256 * i;
    int f = chunk >> 4, c16 = chunk & 15;
    uint4 d = *(const uint4*)(Wta + (size_t)f * CC + c16 * 8);
    unsigned int byte = (unsigned)(f * 256 + c16 * 16) ^ (((unsigned)f & 7) << 4);
    *(uint4*)((char*)wt + byte) = d;
  }
  __syncthreads();

  const int w = t >> 6, l = t & 63, lr = l & 15, lh = l >> 4;
  f32x4 acc[2][8];
#pragma unroll
  for (int a = 0; a < 2; ++a)
#pragma unroll
    for (int n = 0; n < 8; ++n) acc[a][n] = (f32x4){0.f, 0.f, 0.f, 0.f};

#pragma unroll
  for (int kk = 0; kk < 4; ++kk) {
    short8 a[2];
#pragma unroll
    for (int rb = 0; rb < 2; ++rb) {
      int row = w * 32 + rb * 16 + lr;
      unsigned int byte = (unsigned)(row * 256 + kk * 64 + lh * 16) ^ (((unsigned)row & 7) << 4);
      a[rb] = *(const short8*)((const char*)as_ + byte);
    }
#pragma unroll
    for (int n = 0; n < 8; ++n) {
      int row = n * 16 + lr;
      unsigned int byte = (unsigned)(row * 256 + kk * 64 + lh * 16) ^ (((unsigned)row & 7) << 4);
      short8 bfr = *(const short8*)((const char*)wt + byte);
      acc[0][n] = __builtin_amdgcn_mfma_f32_16x16x32_bf16(a[0], bfr, acc[0][n], 0, 0, 0);
      acc[1][n] = __builtin_amdgcn_mfma_f32_16x16x32_bf16(a[1], bfr, acc[1][n], 0, 0, 0);
    }
  }

  const float a0 = alpha[0];
#pragma unroll
  for (int n = 0; n < 8; ++n) {
    int col = n * 16 + lr;
    float bc = ba[col];
#pragma unroll
    for (int rb = 0; rb < 2; ++rb)
#pragma unroll
      for (int r = 0; r < 4; ++r) {
        int row = tile * 128 + w * 32 + rb * 16 + lh * 4 + r;
        size_t idx = (size_t)row * CC + col;
        out[idx] = (acc[rb][n][r] + bc) * a0 * x[idx];
      }
  }
}

// ---------------------------------------------------------------------------
extern "C" void kernel_launch(void* const* d_in, const int* in_sizes, int n_in,
                              void* d_out, int out_size, void* d_ws, size_t ws_size,
                              hipStream_t stream) {
  const float* x     = (const float*)d_in[0];
  const float* Wq    = (const float*)d_in[1];
  const float* bq    = (const float*)d_in[2];
  const float* Wk    = (const float*)d_in[3];
  const float* bk    = (const float*)d_in[4];
  const float* Wv    = (const float*)d_in[5];
  const float* bv    = (const float*)d_in[6];
  const float* Wa    = (const float*)d_in[7];
  const float* ba    = (const float*)d_in[8];
  const float* alpha = (const float*)d_in[9];
  float* out = (float*)d_out;

  char* ws = (char*)d_ws;
  const size_t MAT = (size_t)BB * TT * CC * sizeof(unsigned short); // 8 MiB
  unsigned short* Q  = (unsigned short*)(ws);
  unsigned short* K  = (unsigned short*)(ws + MAT);
  unsigned short* V  = (unsigned short*)(ws + 2 * MAT);
  unsigned short* Vt = (unsigned short*)(ws + 3 * MAT);
  unsigned short* AO = (unsigned short*)(ws + 2 * MAT);  // alias V (dead after vtrans)
  unsigned short* Wt = (unsigned short*)(ws + 4 * MAT);  // 4 x 32 KiB prepped weights

  wprep_kernel<<<dim3(4), 256, 0, stream>>>(Wq, Wk, Wv, Wa, Wt);
  qkv_kernel<<<dim3(256), 256, 0, stream>>>(x, Wt, bq, bk, bv, Q, K, V);
  vtrans_kernel<<<dim3(64, 8), 256, 0, stream>>>(V, Vt);
  flash_kernel<<<dim3(512), 256, 0, stream>>>(Q, K, Vt, AO);
  outproj_kernel<<<dim3(256), 256, 0, stream>>>(AO, Wt + 3 * (size_t)CC * CC, ba, x, alpha, out);
}